// Round 6
// baseline (139.817 us; speedup 1.0000x reference)
//
#include <hip/hip_runtime.h>

#define NB     1024      // systems
#define NDOF   64        // dof per system
#define NSTEPS 200
#define DTF    0.002f

// ---------------- Phase 1: flattened serial chain -> cumulative 2x2 propagators
// One wave per system. Flat chain (round-5 validated numerics: Taylor exp,
// collapsed moment recursion). P stores are BATCHED: lane (n&63) captures
// step n's propagator via cndmask; one contiguous 1KB store per 64 steps.
// => no per-iteration store of loop-carried registers => no per-iter vmcnt.
__global__ __launch_bounds__(256) void nhc_phase1(
    const float* __restrict__ x0, const float* __restrict__ v0,
    const float* __restrict__ kTp, const float* __restrict__ massp,
    const float* __restrict__ Qp, float4* __restrict__ P)
{
    const int tid  = blockIdx.x * blockDim.x + threadIdx.x;
    const int sys  = tid >> 6;
    const int lane = tid & 63;
    if (sys >= NB) return;

    const float kT   = kTp[0];
    const float mass = massp[0];
    const float Q    = Qp[0];

    const float dt   = DTF;
    const float dt2  = 0.5f   * DTF;
    const float dt4  = 0.25f  * DTF;
    const float dt8  = 0.125f * DTF;
    const float invQ = 1.0f / Q;
    const float mi   = mass * invQ;
    const float c    = dt2 / mass;              // half-kick coeff (F = -x)
    const float alpha = 1.0f - dt * c;
    const float gamma = -c * (2.0f - dt * c);   // v' x-coeff (before sc factor)

    // collapsed 2-kick moment map (round-5 validated)
    const float K1 = c * c * (alpha + 1.0f) * (alpha + 1.0f);
    const float K2 = 2.0f * dt * c * c * (alpha + 2.0f) - 4.0f * c;
    const float K3 = alpha * alpha;
    const float A1 = alpha * alpha, A2 = 2.0f * dt * alpha, A3 = dt * dt;
    const float L1 = -c * alpha * (alpha + 1.0f);
    const float L2 = 1.0f - 2.0f * dt * c * (alpha + 1.0f);
    const float L3 = dt * alpha;
    // Taylor: exp(z) ~ 1 + z + z^2/2 (|z| <= ~3e-4)
    const float Bs = -dt8, As = 0.5f * dt8 * dt8;   // s  = exp(-xi1*dt/8)
    const float Bc = -dt2, Ac = 0.5f * dt2 * dt2;   // sc = exp(-xi0*dt/2)
    const float Bu = -dt,  Au = 0.5f * dt * dt;     // u  = exp(-xi0*dt) = sc^2
    const float negC   = -(float)NDOF * kT * invQ;
    const float negkTQ = -kT * invQ;

    const float x = x0[sys * NDOF + lane];
    const float v = v0[sys * NDOF + lane];

    // moment seed (wave-uniform after butterflies), pre-scaled by mass/Q
    float sxx = x * x, sxv = x * v, svv = v * v;
    #pragma unroll
    for (int off = 32; off; off >>= 1) {
        sxx += __shfl_xor(sxx, off, 64);
        sxv += __shfl_xor(sxv, off, 64);
        svv += __shfl_xor(svv, off, 64);
    }
    float Sxx = mi * sxx, Sxv = mi * sxv, Svv = mi * svv;
    float P1 = K1 * Sxx, P2 = K2 * Sxv, P3 = K3 * Svv;

    float xi0 = 0.0f;
    float xi1 = dt4 * (Svv + negC);     // opening increment pre-folded
    float t0  = dt4 * negkTQ;           // dt4*G0 for first iteration (xi0=0)

    // cumulative propagator P = I
    float p00 = 1.0f, p01 = 0.0f, p10 = 0.0f, p11 = 1.0f;
    float k0 = 0.0f, k1 = 0.0f, k2 = 0.0f, k3 = 0.0f;   // per-lane kept step

    for (int n = 0; n < NSTEPS; ++n) {
        // ---- critical scalar chain (~14 dependent fma) ----
        float s  = fmaf(xi1, fmaf(As, xi1, Bs), 1.0f);
        xi0 = fmaf(xi0, s, t0) * s;
        float sc = fmaf(xi0, fmaf(Ac, xi0, Bc), 1.0f);
        float u  = fmaf(xi0, fmaf(Au, xi0, Bu), 1.0f);
        float b  = fmaf(u, P3, fmaf(sc, P2, P1));
        float Gt = fmaf(u, b, negC);
        float t  = dt4 * Gt;
        xi0 = fmaf(xi0, s, t) * s;
        float G1 = fmaf(xi0, xi0, negkTQ);
        xi1 = xi1 + fmaf(dt4, G1, t);
        t0  = dt4 * G1;

        // ---- off-critical: moment state + P precompute ----
        float X = sc * Sxv, V = u * Svv;
        float Sxx1 = fmaf(A1, Sxx, fmaf(A2, X, A3 * V));
        Sxv = sc * fmaf(L1, Sxx, fmaf(L2, X, L3 * V));
        Svv = u * b;
        Sxx = Sxx1;
        P1 = K1 * Sxx; P2 = K2 * Sxv; P3 = K3 * Svv;

        // ---- off-critical: compose propagator P = M_n * P ----
        float bb = dt * sc, g = gamma * sc, a2 = alpha * u;
        float q00 = fmaf(alpha, p00, bb * p10);
        float q01 = fmaf(alpha, p01, bb * p11);
        float q10 = fmaf(g,     p00, a2 * p10);
        float q11 = fmaf(g,     p01, a2 * p11);
        p00 = q00; p01 = q01; p10 = q10; p11 = q11;

        // ---- keep-select: lane (n&63) captures this step's propagator ----
        const bool sel = (lane == (n & 63));
        k0 = sel ? p00 : k0;
        k1 = sel ? p01 : k1;
        k2 = sel ? p10 : k2;
        k3 = sel ? p11 : k3;

        // ---- batched store: one contiguous 1KB store per 64 steps ----
        if ((n & 63) == 63) {
            P[sys * NSTEPS + (n - 63) + lane] = make_float4(k0, k1, k2, k3);
        }
    }
    // tail: steps 192..199 held by lanes 0..7
    if (lane < (NSTEPS & 63)) {
        P[sys * NSTEPS + (NSTEPS & ~63) + lane] = make_float4(k0, k1, k2, k3);
    }
}

// ---------------- Phase 2: embarrassingly-parallel trajectory materialization
// (measured ~18 us in round 4 at 12864 blocks — near store-BW limit)
#define F4_PER_SYS  (NDOF / 4)                  // 16
#define F4_PER_STEP (NB * F4_PER_SYS)           // 16384 = 2^14
#define TOTAL_F4    ((NSTEPS + 1) * F4_PER_STEP)

__global__ __launch_bounds__(256) void nhc_phase2(
    const float* __restrict__ x0, const float* __restrict__ v0,
    const float4* __restrict__ P, float* __restrict__ out)
{
    const int t = blockIdx.x * blockDim.x + threadIdx.x;
    if (t >= TOTAL_F4) return;

    const int step = t >> 14;
    const int rem  = t & (F4_PER_STEP - 1);
    const int sys  = rem >> 4;
    const int q    = rem & 15;

    const float4 xv = *reinterpret_cast<const float4*>(&x0[sys * NDOF + q * 4]);
    const float4 vv = *reinterpret_cast<const float4*>(&v0[sys * NDOF + q * 4]);

    const size_t o = (size_t)step * (NB * NDOF) + sys * NDOF + q * 4;
    float4* __restrict__ ox = reinterpret_cast<float4*>(&out[o]);
    float4* __restrict__ ov = reinterpret_cast<float4*>(
        &out[o + (size_t)(NSTEPS + 1) * NB * NDOF]);

    if (step == 0) {     // whole blocks per step -> no intra-wave divergence
        *ox = xv;
        *ov = vv;
        return;
    }
    const float4 p = P[sys * NSTEPS + (step - 1)];
    float4 rx, rv;
    rx.x = fmaf(p.x, xv.x, p.y * vv.x);  rv.x = fmaf(p.z, xv.x, p.w * vv.x);
    rx.y = fmaf(p.x, xv.y, p.y * vv.y);  rv.y = fmaf(p.z, xv.y, p.w * vv.y);
    rx.z = fmaf(p.x, xv.z, p.y * vv.z);  rv.z = fmaf(p.z, xv.z, p.w * vv.z);
    rx.w = fmaf(p.x, xv.w, p.y * vv.w);  rv.w = fmaf(p.z, xv.w, p.w * vv.w);
    *ox = rx;
    *ov = rv;
}

// ---------------- Fallback (round-5 fused kernel) if workspace too small
__global__ __launch_bounds__(256) void nhc_fused(
    const float* __restrict__ x0, const float* __restrict__ v0,
    const float* __restrict__ kTp, const float* __restrict__ massp,
    const float* __restrict__ Qp, float* __restrict__ out)
{
    const int tid  = blockIdx.x * blockDim.x + threadIdx.x;
    const int sys  = tid >> 6;
    const int lane = tid & 63;
    if (sys >= NB) return;

    const float kT = kTp[0], mass = massp[0], Q = Qp[0];
    const float dt = DTF, dt2 = 0.5f*DTF, dt4 = 0.25f*DTF, dt8 = 0.125f*DTF;
    const float invQ = 1.0f/Q, mi = mass*invQ, c = dt2/mass;
    const float alpha = 1.0f - dt*c;
    const float K1 = c*c*(alpha+1.0f)*(alpha+1.0f);
    const float K2 = 2.0f*dt*c*c*(alpha+2.0f) - 4.0f*c;
    const float K3 = alpha*alpha;
    const float A1 = alpha*alpha, A2 = 2.0f*dt*alpha, A3 = dt*dt;
    const float L1 = -c*alpha*(alpha+1.0f);
    const float L2 = 1.0f - 2.0f*dt*c*(alpha+1.0f);
    const float L3 = dt*alpha;
    const float Bs = -dt8, As = 0.5f*dt8*dt8;
    const float Bc = -dt2, Ac = 0.5f*dt2*dt2;
    const float Bu = -dt,  Au = 0.5f*dt*dt;
    const float negC = -(float)NDOF*kT*invQ, negkTQ = -kT*invQ;

    float x = x0[sys*NDOF+lane], v = v0[sys*NDOF+lane];
    float* __restrict__ out_x = out;
    float* __restrict__ out_v = out + (size_t)(NSTEPS+1)*NB*NDOF;
    out_x[sys*NDOF+lane] = x;  out_v[sys*NDOF+lane] = v;

    float sxx = x*x, sxv = x*v, svv = v*v;
    #pragma unroll
    for (int off = 32; off; off >>= 1) {
        sxx += __shfl_xor(sxx, off, 64);
        sxv += __shfl_xor(sxv, off, 64);
        svv += __shfl_xor(svv, off, 64);
    }
    float Sxx = mi*sxx, Sxv = mi*sxv, Svv = mi*svv;
    float P1 = K1*Sxx, P2 = K2*Sxv, P3 = K3*Svv;
    float xi0 = 0.0f, xi1 = dt4*(Svv+negC), t0 = dt4*negkTQ;
    size_t widx = (size_t)NB*NDOF + sys*NDOF + lane;

    for (int n = 0; n < NSTEPS; ++n) {
        float s  = fmaf(xi1, fmaf(As, xi1, Bs), 1.0f);
        xi0 = fmaf(xi0, s, t0) * s;
        float sc = fmaf(xi0, fmaf(Ac, xi0, Bc), 1.0f);
        float u  = fmaf(xi0, fmaf(Au, xi0, Bu), 1.0f);
        float b  = fmaf(u, P3, fmaf(sc, P2, P1));
        float Gt = fmaf(u, b, negC);
        float t  = dt4 * Gt;
        xi0 = fmaf(xi0, s, t) * s;
        float G1 = fmaf(xi0, xi0, negkTQ);
        xi1 = xi1 + fmaf(dt4, G1, t);
        t0  = dt4 * G1;
        float X = sc*Sxv, V = u*Svv;
        float Sxx1 = fmaf(A1, Sxx, fmaf(A2, X, A3*V));
        Sxv = sc*fmaf(L1, Sxx, fmaf(L2, X, L3*V));
        Svv = u*b;  Sxx = Sxx1;
        P1 = K1*Sxx; P2 = K2*Sxv; P3 = K3*Svv;
        v *= sc;  v = fmaf(-c,x,v);  x = fmaf(dt,v,x);  v = fmaf(-c,x,v);  v *= sc;
        out_x[widx] = x;  out_v[widx] = v;
        widx += (size_t)NB*NDOF;
    }
}

extern "C" void kernel_launch(void* const* d_in, const int* in_sizes, int n_in,
                              void* d_out, int out_size, void* d_ws, size_t ws_size,
                              hipStream_t stream) {
    const float* x0   = (const float*)d_in[0];
    const float* v0   = (const float*)d_in[1];
    const float* kT   = (const float*)d_in[2];
    const float* mass = (const float*)d_in[3];
    const float* Q    = (const float*)d_in[4];
    float* out = (float*)d_out;

    const size_t ws_needed = (size_t)NB * NSTEPS * 4 * sizeof(float); // 3.28 MB
    if (ws_size < ws_needed) {
        nhc_fused<<<NB * NDOF / 256, 256, 0, stream>>>(x0, v0, kT, mass, Q, out);
        return;
    }
    float4* P = (float4*)d_ws;

    nhc_phase1<<<NB * NDOF / 256, 256, 0, stream>>>(x0, v0, kT, mass, Q, P);

    const int blocks = TOTAL_F4 / 256;     // 12864 (exact)
    nhc_phase2<<<blocks, 256, 0, stream>>>(x0, v0, P, out);
}

// Round 7
// 122.901 us; speedup vs baseline: 1.1376x; 1.1376x over previous
//
#include <hip/hip_runtime.h>

#define NB     1024      // systems
#define NDOF   64        // dof per system
#define NSTEPS 200
#define DTF    0.002f

// One wave (64 lanes) per system; lane == dof. Fused kernel, minimal critical
// chain (~10 dependent fma/step):
//  - Gt collapsed to a 2nd-order Taylor in xi0m with coefficients g0,g1,g2
//    precomputed OFF-path from the previous step's moments
//    (Gt = P1 e^-e + P2 e^-1.5e + P3 e^-2e + negC, e = dt*xi0m, |e|~4e-3,
//     err ~ |P|*e^3 ~ 4e-6 -> invisible at threshold 8.9e-2)
//  - Svv' = Gt - negC exactly (consistency preserved, 1 op)
//  - second xi0 half-step folded: xi0f = fmaf(xi0m, s^2, (dt4*s)*Gt)
//  - exp -> 2nd-order Taylor everywhere (|z| <= ~4e-3)
__global__ __launch_bounds__(256) void nhc_kernel(
    const float* __restrict__ x0, const float* __restrict__ v0,
    const float* __restrict__ kTp, const float* __restrict__ massp,
    const float* __restrict__ Qp, float* __restrict__ out)
{
    const int tid  = blockIdx.x * blockDim.x + threadIdx.x;
    const int sys  = tid >> 6;
    const int lane = tid & 63;
    if (sys >= NB) return;

    const float kT   = kTp[0];
    const float mass = massp[0];
    const float Q    = Qp[0];

    const float dt   = DTF;
    const float dt2  = 0.5f   * DTF;
    const float dt4  = 0.25f  * DTF;
    const float dt8  = 0.125f * DTF;
    const float invQ = 1.0f / Q;
    const float mi   = mass * invQ;
    const float c    = dt2 / mass;              // half-kick coeff (F = -x)
    const float alpha = 1.0f - dt * c;

    // collapsed 2-kick moment map (validated r5/r6)
    const float K1 = c * c * (alpha + 1.0f) * (alpha + 1.0f);
    const float K2 = 2.0f * dt * c * c * (alpha + 2.0f) - 4.0f * c;
    const float K3 = alpha * alpha;
    const float A1 = alpha * alpha, A2 = 2.0f * dt * alpha, A3 = dt * dt;
    const float L1 = -c * alpha * (alpha + 1.0f);
    const float L2 = 1.0f - 2.0f * dt * c * (alpha + 1.0f);
    const float L3 = dt * alpha;
    // Gt-Taylor coefficient generators (g = D·moments):
    const float D1 = -dt * K1,            D2 = -1.5f * dt * K2,        D3 = -2.0f * dt * K3;
    const float E1 = 0.5f * dt * dt * K1, E2 = 1.125f * dt * dt * K2,  E3 = 2.0f * dt * dt * K3;
    // exp Taylor: exp(z) ~ 1 + z + z^2/2
    const float Bs = -dt8, As = 0.5f * dt8 * dt8;   // s  = exp(-xi1*dt/8)
    const float Bc = -dt2, Ac = 0.5f * dt2 * dt2;   // sc = exp(-xi0*dt/2)
    const float Bu = -dt,  Au = 0.5f * dt * dt;     // u  = exp(-xi0*dt)
    const float negC   = -(float)NDOF * kT * invQ;
    const float posC   = -negC;
    const float negkTQ = -kT * invQ;

    float x = x0[sys * NDOF + lane];
    float v = v0[sys * NDOF + lane];

    float* __restrict__ out_x = out;
    float* __restrict__ out_v = out + (size_t)(NSTEPS + 1) * NB * NDOF;

    const int base = sys * NDOF + lane;
    out_x[base] = x;
    out_v[base] = v;

    // one-time moment seed (wave-uniform after butterflies), pre-scaled mass/Q
    float sxx = x * x, sxv = x * v, svv = v * v;
    #pragma unroll
    for (int off = 32; off; off >>= 1) {
        sxx += __shfl_xor(sxx, off, 64);
        sxv += __shfl_xor(sxv, off, 64);
        svv += __shfl_xor(svv, off, 64);
    }
    float Sxx = mi * sxx, Sxv = mi * sxv, Svv = mi * svv;
    float g0 = fmaf(K1, Sxx, fmaf(K2, Sxv, fmaf(K3, Svv, negC)));
    float g1 = fmaf(D1, Sxx, fmaf(D2, Sxv, D3 * Svv));
    float g2 = fmaf(E1, Sxx, fmaf(E2, Sxv, E3 * Svv));

    float xi0 = 0.0f;
    float xi1 = dt4 * (Svv + negC);     // opening increment pre-folded
    float t0  = dt4 * negkTQ;           // dt4*G0 for first iteration (xi0=0)

    int widx = NB * NDOF + base;        // step-1 slot (max idx < 2^25)

    #pragma unroll 2
    for (int n = 0; n < NSTEPS; ++n) {
        // ---- critical scalar chain (~10 dependent fma) ----
        float s    = fmaf(xi1, fmaf(As, xi1, Bs), 1.0f);   // 2 deps
        float xi0m = fmaf(xi0, s, t0) * s;                 // 2 deps
        float S2   = s * s;                                // off-path
        float dt4s = dt4 * s;                              // off-path
        float Gt   = fmaf(xi0m, fmaf(g2, xi0m, g1), g0);   // 2 deps
        float e    = fmaf(dt4, Gt, xi1);                   // off-path (lvl 7)
        float xi0f = fmaf(xi0m, S2, dt4s * Gt);            // 2 deps
        float G1   = xi0f * xi0f;                          // 1 dep
        xi1 = fmaf(dt4, G1, e);                            // 1 dep
        t0  = dt4 * G1;                                    // parallel
        xi0 = xi0f;

        // ---- off-critical: sc,u + moment state + g precompute ----
        float sc = fmaf(xi0m, fmaf(Ac, xi0m, Bc), 1.0f);
        float u  = fmaf(xi0m, fmaf(Au, xi0m, Bu), 1.0f);
        float X  = sc * Sxv, V = u * Svv;
        float Sxx1 = fmaf(A1, Sxx, fmaf(A2, X, A3 * V));
        Sxv = sc * fmaf(L1, Sxx, fmaf(L2, X, L3 * V));
        Svv = Gt + posC;                                   // = u*b exactly
        Sxx = Sxx1;
        g0 = fmaf(K1, Sxx, fmaf(K2, Sxv, fmaf(K3, Svv, negC)));
        g1 = fmaf(D1, Sxx, fmaf(D2, Sxv, D3 * Svv));
        g2 = fmaf(E1, Sxx, fmaf(E2, Sxv, E3 * Svv));

        // ---- off-critical: per-dof trajectory + stores ----
        v *= sc;
        v = fmaf(-c, x, v);
        x = fmaf(dt, v, x);
        v = fmaf(-c, x, v);
        v *= sc;

        out_x[widx] = x;
        out_v[widx] = v;
        widx += NB * NDOF;
    }
}

extern "C" void kernel_launch(void* const* d_in, const int* in_sizes, int n_in,
                              void* d_out, int out_size, void* d_ws, size_t ws_size,
                              hipStream_t stream) {
    const float* x0   = (const float*)d_in[0];
    const float* v0   = (const float*)d_in[1];
    const float* kT   = (const float*)d_in[2];
    const float* mass = (const float*)d_in[3];
    const float* Q    = (const float*)d_in[4];
    float* out = (float*)d_out;

    const int total = NB * NDOF;           // 65536 threads
    const int block = 256;
    const int grid  = total / block;       // 256 blocks, 1 block/CU
    nhc_kernel<<<grid, block, 0, stream>>>(x0, v0, kT, mass, Q, out);
}